// Round 1
// baseline (287.805 us; speedup 1.0000x reference)
//
#include <hip/hip_runtime.h>
#include <hip/hip_bf16.h>
#include <stdint.h>

#define BATCH 4
#define SEQ   2048
#define DIN   1024
#define DOUT  1024
#define MTOT  (BATCH*SEQ)   // 8192

typedef __attribute__((ext_vector_type(8))) short bf16x8;
typedef __attribute__((ext_vector_type(4))) float f32x4;

__device__ inline unsigned short f2bf(float f) {
  union { float f; unsigned u; } a; a.f = f;
  unsigned r = a.u + 0x7fffu + ((a.u >> 16) & 1u);   // RTNE
  return (unsigned short)(r >> 16);
}

__device__ inline void gload_lds16(const void* g, void* l) {
  __builtin_amdgcn_global_load_lds(
      (__attribute__((address_space(1))) void*)(uintptr_t)(g),
      (__attribute__((address_space(3))) void*)(uintptr_t)(l),
      16, 0, 0);
}

// ---------------------------------------------------------------- convert ---
// x (8.39M f32) -> xb bf16 ; Wk,Wq -> wkqb [2048][1024] ; Wv -> wvb
__global__ __launch_bounds__(256)
void convert_kernel(const float* __restrict__ x, const float* __restrict__ wk,
                    const float* __restrict__ wq, const float* __restrict__ wv,
                    unsigned short* __restrict__ xb, unsigned short* __restrict__ wkqb,
                    unsigned short* __restrict__ wvb) {
  const long NX = (long)MTOT * DIN;      // 8388608
  const long NW = (long)DOUT * DIN;      // 1048576
  long t = (long)blockIdx.x * blockDim.x + threadIdx.x;
  long off = t * 4;
  if (off >= NX + 3 * NW) return;
  const float* src; unsigned short* dst; long o;
  if (off < NX)            { src = x;  dst = xb;        o = off; }
  else if (off < NX + NW)  { src = wk; dst = wkqb;      o = off - NX; }
  else if (off < NX + 2*NW){ src = wq; dst = wkqb + NW; o = off - NX - NW; }
  else                     { src = wv; dst = wvb;       o = off - NX - 2*NW; }
  f32x4 v = *(const f32x4*)(src + o);
  unsigned p0 = (unsigned)f2bf(v[0]) | ((unsigned)f2bf(v[1]) << 16);
  unsigned p1 = (unsigned)f2bf(v[2]) | ((unsigned)f2bf(v[3]) << 16);
  uint2* d = (uint2*)(dst + o);
  *d = make_uint2(p0, p1);
}

// ------------------------------------------------------------------- GEMM ---
// C[M][N] = A[M][K] * Bw[N][K]^T   (all row-major, K contiguous in A and Bw)
// 128x128 tile, BK=64, 4 waves (2x2), each wave 64x64 via 4x4 16x16x32 MFMA.
#define BM 128
#define BN 128
#define BK 64

__global__ __launch_bounds__(256, 2)
void gemm_kernel(const unsigned short* __restrict__ A,
                 const unsigned short* __restrict__ Bw,
                 void* __restrict__ Cout,
                 int lda, int ldb, int ldc, int K,
                 long aBatch, long bBatch, long cBatch,
                 float scale, int outBf16, int tri, int klimit) {
  int bj = blockIdx.x, bi = blockIdx.y, b = blockIdx.z;
  if (tri && bj > bi) return;                  // causal block skip
  int Keff = K;
  if (klimit) { int km = (bi + 1) * BM; Keff = km < K ? km : K; }

  const unsigned short* Ab = A  + (long)b * aBatch + (long)bi * BM * lda;
  const unsigned short* Bb = Bw + (long)b * bBatch + (long)bj * BN * ldb;

  __shared__ unsigned short at[BM * BK];   // [128][64] bf16, 16 KiB
  __shared__ unsigned short bt[BN * BK];

  const int tid  = threadIdx.x;
  const int lane = tid & 63;
  const int w    = tid >> 6;       // wave 0..3
  const int wm   = w >> 1;         // wave row (0..1) -> 64 rows
  const int wn   = w & 1;          // wave col (0..1) -> 64 cols

  f32x4 acc[4][4];
#pragma unroll
  for (int i = 0; i < 4; i++)
#pragma unroll
    for (int j = 0; j < 4; j++) acc[i][j] = (f32x4){0.f, 0.f, 0.f, 0.f};

  const int srow = lane >> 3;        // 0..7
  const int scol = (lane & 7) * 8;   // 0..56 (elements)

  const int ntiles = Keff / BK;
  for (int kt = 0; kt < ntiles; ++kt) {
    const int k0 = kt * BK;
    if (kt) __syncthreads();
#pragma unroll
    for (int t = 0; t < 4; t++) {
      const int r = w * 32 + t * 8 + srow;
      gload_lds16(Ab + (long)r * lda + k0 + scol, &at[(w * 32 + t * 8) * BK + lane * 8]);
      gload_lds16(Bb + (long)r * ldb + k0 + scol, &bt[(w * 32 + t * 8) * BK + lane * 8]);
    }
    asm volatile("s_waitcnt vmcnt(0)" ::: "memory");
    __syncthreads();
#pragma unroll
    for (int kk = 0; kk < 2; ++kk) {
      bf16x8 af[4], bfr[4];
#pragma unroll
      for (int i = 0; i < 4; i++)
        af[i] = *(const bf16x8*)&at[(wm * 64 + i * 16 + (lane & 15)) * BK + kk * 32 + (lane >> 4) * 8];
#pragma unroll
      for (int j = 0; j < 4; j++)
        bfr[j] = *(const bf16x8*)&bt[(wn * 64 + j * 16 + (lane & 15)) * BK + kk * 32 + (lane >> 4) * 8];
#pragma unroll
      for (int i = 0; i < 4; i++)
#pragma unroll
        for (int j = 0; j < 4; j++)
          acc[i][j] = __builtin_amdgcn_mfma_f32_16x16x32_bf16(af[i], bfr[j], acc[i][j], 0, 0, 0);
    }
  }

  const long crow0 = (long)bi * BM + wm * 64;
  const long ccol0 = (long)bj * BN + wn * 64;
  if (outBf16) {
    unsigned short* C = (unsigned short*)Cout + (long)b * cBatch;
#pragma unroll
    for (int i = 0; i < 4; i++) {
      const long row0 = crow0 + i * 16 + ((lane >> 4) << 2);
#pragma unroll
      for (int j = 0; j < 4; j++) {
        const long col = ccol0 + j * 16 + (lane & 15);
#pragma unroll
        for (int r2 = 0; r2 < 4; r2++)
          C[(row0 + r2) * ldc + col] = f2bf(acc[i][j][r2] * scale);
      }
    }
  } else {
    float* C = (float*)Cout + (long)b * cBatch;
#pragma unroll
    for (int i = 0; i < 4; i++) {
      const long row0 = crow0 + i * 16 + ((lane >> 4) << 2);
#pragma unroll
      for (int j = 0; j < 4; j++) {
        const long col = ccol0 + j * 16 + (lane & 15);
#pragma unroll
        for (int r2 = 0; r2 < 4; r2++)
          C[(row0 + r2) * ldc + col] = acc[i][j][r2] * scale;
      }
    }
  }
}

// ---------------------------------------------------------------- softmax ---
// One block per (b, i) row. Reads scores[r][0..i], writes P[r][0..i] bf16,
// zero-fills P up to the 128-block boundary the PV GEMM will read.
__global__ __launch_bounds__(256)
void softmax_kernel(const float* __restrict__ scores, unsigned short* __restrict__ P) {
  __shared__ float rowbuf[SEQ];   // 8 KiB
  __shared__ float red[8];
  const int r = blockIdx.x;               // 0..8191
  const int i = r & (SEQ - 1);
  const int n = i + 1;
  const int kend = ((i >> 7) + 1) << 7;   // next 128 boundary
  const float* src = scores + (long)r * SEQ;
  unsigned short* dst = P + (long)r * SEQ;
  const int tid = threadIdx.x;

  float m = -1e30f;
  for (int j = tid; j < n; j += 256) { float v = src[j]; rowbuf[j] = v; m = fmaxf(m, v); }
#pragma unroll
  for (int o = 32; o; o >>= 1) m = fmaxf(m, __shfl_down(m, o, 64));
  if ((tid & 63) == 0) red[tid >> 6] = m;
  __syncthreads();
  m = fmaxf(fmaxf(red[0], red[1]), fmaxf(red[2], red[3]));

  float s = 0.f;
  for (int j = tid; j < n; j += 256) { float e = __expf(rowbuf[j] - m); rowbuf[j] = e; s += e; }
#pragma unroll
  for (int o = 32; o; o >>= 1) s += __shfl_down(s, o, 64);
  if ((tid & 63) == 0) red[4 + (tid >> 6)] = s;
  __syncthreads();
  s = red[4] + red[5] + red[6] + red[7];
  const float inv = 1.0f / s;

  for (int j = tid; j < n; j += 256) dst[j] = f2bf(rowbuf[j] * inv);
  for (int j = n + tid; j < kend; j += 256) dst[j] = 0;
}

// ----------------------------------------------------------------- launch ---
extern "C" void kernel_launch(void* const* d_in, const int* in_sizes, int n_in,
                              void* d_out, int out_size, void* d_ws, size_t ws_size,
                              hipStream_t stream) {
  const float* x  = (const float*)d_in[0];
  const float* Wk = (const float*)d_in[1];
  const float* Wq = (const float*)d_in[2];
  const float* Wv = (const float*)d_in[3];

  char* ws = (char*)d_ws;
  unsigned short* xb   = (unsigned short*)(ws);                 // [8192][1024] bf16
  unsigned short* qk   = (unsigned short*)(ws + 16777216);      // [8192][2048] bf16 (q | k)
  unsigned short* vtb  = (unsigned short*)(ws + 50331648);      // [1024][8192] bf16 (V^T)
  unsigned short* wkqb = (unsigned short*)(ws + 67108864);      // [2048][1024] bf16
  unsigned short* wvb  = (unsigned short*)(ws + 71303168);      // [1024][1024] bf16
  float*          scores = (float*)(ws + 73400320);             // [4][2048][2048] f32
  unsigned short* P    = (unsigned short*)(ws + 140509184);     // [4][2048][2048] bf16
  float* out = (float*)d_out;

  // 1. fp32 -> bf16 conversions
  {
    long total4 = ((long)MTOT * DIN + 3L * DOUT * DIN) / 4;   // 2883584
    int blocks = (int)((total4 + 255) / 256);
    convert_kernel<<<dim3(blocks), dim3(256), 0, stream>>>(x, Wk, Wq, Wv, xb, wkqb, wvb);
  }
  // 2. qk[m][0:1024]=q (x@Wk^T), qk[m][1024:2048]=k (x@Wq^T): M=8192 N=2048 K=1024
  gemm_kernel<<<dim3(2048 / BN, 8192 / BM, 1), dim3(256), 0, stream>>>(
      xb, wkqb, qk, 1024, 1024, 2048, 1024, 0L, 0L, 0L, 1.0f, 1, 0, 0);
  // 3. vT[e][m] = Wv@x^T: M=1024 N=8192 K=1024
  gemm_kernel<<<dim3(8192 / BN, 1024 / BM, 1), dim3(256), 0, stream>>>(
      wvb, xb, vtb, 1024, 1024, 8192, 1024, 0L, 0L, 0L, 1.0f, 1, 0, 0);
  // 4. scores = q@k^T * 1/sqrt(1024), causal lower-tri blocks only, per batch
  gemm_kernel<<<dim3(16, 16, BATCH), dim3(256), 0, stream>>>(
      qk, qk + 1024, scores, 2048, 2048, 2048, 1024,
      (long)SEQ * 2048, (long)SEQ * 2048, (long)SEQ * SEQ, 0.03125f, 0, 1, 0);
  // 5. row softmax -> P (bf16), zero-filled to 128 boundary
  softmax_kernel<<<dim3(BATCH * SEQ), dim3(256), 0, stream>>>(scores, P);
  // 6. out = P@V: M=2048 N=1024 K<= (bi+1)*128, per batch
  gemm_kernel<<<dim3(1024 / BN, 2048 / BM, BATCH), dim3(256), 0, stream>>>(
      P, vtb, out, 2048, 8192, 1024, 2048,
      (long)SEQ * SEQ, 2048L, (long)SEQ * DOUT, 1.0f, 0, 0, 1);
}

// Round 2
// 265.865 us; speedup vs baseline: 1.0825x; 1.0825x over previous
//
#include <hip/hip_runtime.h>
#include <hip/hip_bf16.h>
#include <stdint.h>

#define BATCH 4
#define SEQ   2048
#define DIN   1024
#define DOUT  1024
#define MTOT  (BATCH*SEQ)   // 8192

typedef __attribute__((ext_vector_type(8))) short bf16x8;
typedef __attribute__((ext_vector_type(4))) float f32x4;

__device__ inline unsigned short f2bf(float f) {
  union { float f; unsigned u; } a; a.f = f;
  unsigned r = a.u + 0x7fffu + ((a.u >> 16) & 1u);   // RTNE
  return (unsigned short)(r >> 16);
}
__device__ inline float bf2f(unsigned short b) {
  union { unsigned u; float f; } a; a.u = ((unsigned)b) << 16; return a.f;
}

__device__ inline void gload_lds16(const void* g, void* l) {
  __builtin_amdgcn_global_load_lds(
      (__attribute__((address_space(1))) void*)(uintptr_t)(g),
      (__attribute__((address_space(3))) void*)(uintptr_t)(l),
      16, 0, 0);
}

// ---------------------------------------------------------------- convert ---
__global__ __launch_bounds__(256)
void convert_kernel(const float* __restrict__ x, const float* __restrict__ wk,
                    const float* __restrict__ wq, const float* __restrict__ wv,
                    unsigned short* __restrict__ xb, unsigned short* __restrict__ wkqb,
                    unsigned short* __restrict__ wvb) {
  const long NX = (long)MTOT * DIN;      // 8388608
  const long NW = (long)DOUT * DIN;      // 1048576
  long t = (long)blockIdx.x * blockDim.x + threadIdx.x;
  long off = t * 4;
  if (off >= NX + 3 * NW) return;
  const float* src; unsigned short* dst; long o;
  if (off < NX)            { src = x;  dst = xb;        o = off; }
  else if (off < NX + NW)  { src = wk; dst = wkqb;      o = off - NX; }
  else if (off < NX + 2*NW){ src = wq; dst = wkqb + NW; o = off - NX - NW; }
  else                     { src = wv; dst = wvb;       o = off - NX - 2*NW; }
  f32x4 v = *(const f32x4*)(src + o);
  unsigned p0 = (unsigned)f2bf(v[0]) | ((unsigned)f2bf(v[1]) << 16);
  unsigned p1 = (unsigned)f2bf(v[2]) | ((unsigned)f2bf(v[3]) << 16);
  uint2* d = (uint2*)(dst + o);
  *d = make_uint2(p0, p1);
}

// ----------------------------------------------------- 256x256 2-phase GEMM ---
// C[M][N] = A[M][K] * Bw[N][K]^T, bf16 out. 8 waves (2Mx4N), per-wave 128x64.
// Double-buffered LDS (128 KiB), stage-next-then-compute, 1 barrier pair/tile.
#define TBM 256
#define TBN 256
#define TBK 64

__global__ __launch_bounds__(512, 2)
void gemm256_kernel(const unsigned short* __restrict__ A,
                    const unsigned short* __restrict__ Bw,
                    unsigned short* __restrict__ C,
                    int lda, int ldb, int ldc, int K) {
  const int bj = blockIdx.x, bi = blockIdx.y;
  const unsigned short* Ab = A + (long)bi * TBM * lda;
  const unsigned short* Bb = Bw + (long)bj * TBN * ldb;

  __shared__ unsigned short at[2][TBM * TBK];   // 2 x 32 KiB
  __shared__ unsigned short bt[2][TBN * TBK];   // 2 x 32 KiB

  const int tid  = threadIdx.x;
  const int lane = tid & 63;
  const int w    = tid >> 6;       // 0..7
  const int wm   = w >> 2;         // 0..1 -> 128 rows
  const int wn   = w & 3;          // 0..3 -> 64 cols

  f32x4 acc[8][4];
#pragma unroll
  for (int i = 0; i < 8; i++)
#pragma unroll
    for (int j = 0; j < 4; j++) acc[i][j] = (f32x4){0.f, 0.f, 0.f, 0.f};

  const int srow = lane >> 3;        // 0..7
  const int scol = (lane & 7) * 8;   // 0..56

  const int nt = K / TBK;

#define STAGE256(buf, kt)                                                          \
  {                                                                                \
    const int k0 = (kt) * TBK;                                                     \
    _Pragma("unroll")                                                              \
    for (int c = 0; c < 4; c++) {                                                  \
      const int rr = (w * 4 + c) * 8;                                              \
      gload_lds16(Ab + (long)(rr + srow) * lda + k0 + scol,                        \
                  &at[buf][rr * TBK + lane * 8]);                                  \
    }                                                                              \
    _Pragma("unroll")                                                              \
    for (int c = 0; c < 4; c++) {                                                  \
      const int rr = (w * 4 + c) * 8;                                              \
      gload_lds16(Bb + (long)(rr + srow) * ldb + k0 + scol,                        \
                  &bt[buf][rr * TBK + lane * 8]);                                  \
    }                                                                              \
  }

#define COMPUTE256(buf)                                                            \
  {                                                                                \
    _Pragma("unroll")                                                              \
    for (int kk = 0; kk < 2; kk++) {                                               \
      bf16x8 af[8], bfr[4];                                                        \
      _Pragma("unroll")                                                            \
      for (int i = 0; i < 8; i++)                                                  \
        af[i] = *(const bf16x8*)&at[buf][(wm * 128 + i * 16 + (lane & 15)) * TBK   \
                                         + kk * 32 + (lane >> 4) * 8];             \
      _Pragma("unroll")                                                            \
      for (int j = 0; j < 4; j++)                                                  \
        bfr[j] = *(const bf16x8*)&bt[buf][(wn * 64 + j * 16 + (lane & 15)) * TBK   \
                                          + kk * 32 + (lane >> 4) * 8];            \
      __builtin_amdgcn_s_setprio(1);                                               \
      _Pragma("unroll")                                                            \
      for (int i = 0; i < 8; i++)                                                  \
        _Pragma("unroll")                                                          \
        for (int j = 0; j < 4; j++)                                                \
          acc[i][j] = __builtin_amdgcn_mfma_f32_16x16x32_bf16(af[i], bfr[j],       \
                                                              acc[i][j], 0, 0, 0); \
      __builtin_amdgcn_s_setprio(0);                                               \
    }                                                                              \
  }

  STAGE256(0, 0);
  asm volatile("s_waitcnt vmcnt(0)" ::: "memory");
  __syncthreads();

  for (int kt = 0; kt < nt - 1; ++kt) {
    const int cur = kt & 1;
    STAGE256(cur ^ 1, kt + 1);     // issue next-tile loads first
    COMPUTE256(cur);               // ds_read + MFMA on current
    asm volatile("s_waitcnt vmcnt(0)" ::: "memory");
    __syncthreads();
  }
  COMPUTE256((nt - 1) & 1);

  const long crow0 = (long)bi * TBM + wm * 128;
  const long ccol0 = (long)bj * TBN + wn * 64;
#pragma unroll
  for (int i = 0; i < 8; i++) {
    const long row0 = crow0 + i * 16 + ((lane >> 4) << 2);
#pragma unroll
    for (int j = 0; j < 4; j++) {
      const long col = ccol0 + j * 16 + (lane & 15);
#pragma unroll
      for (int r2 = 0; r2 < 4; r2++)
        C[(row0 + r2) * ldc + col] = f2bf(acc[i][j][r2]);
    }
  }
#undef STAGE256
#undef COMPUTE256
}

// ----------------------------------------------------------- 128x128 GEMM ---
#define BM 128
#define BN 128
#define BK 64

__global__ __launch_bounds__(256, 2)
void gemm_kernel(const unsigned short* __restrict__ A,
                 const unsigned short* __restrict__ Bw,
                 void* __restrict__ Cout,
                 int lda, int ldb, int ldc, int K,
                 long aBatch, long bBatch, long cBatch,
                 float scale, int outBf16, int triPack, int klimit) {
  int bj = blockIdx.x, bi = blockIdx.y, b = blockIdx.z;
  if (triPack) {                      // exact lower-tri grid: decode linear idx
    int idx = blockIdx.x;
    int t = (int)((sqrtf(8.f * idx + 1.f) - 1.f) * 0.5f);
    while ((t + 1) * (t + 2) / 2 <= idx) t++;
    while (t * (t + 1) / 2 > idx) t--;
    bi = t; bj = idx - t * (t + 1) / 2;
  }
  int Keff = K;
  if (klimit) { int km = (bi + 1) * BM; Keff = km < K ? km : K; }

  const unsigned short* Ab = A  + (long)b * aBatch + (long)bi * BM * lda;
  const unsigned short* Bb = Bw + (long)b * bBatch + (long)bj * BN * ldb;

  __shared__ unsigned short at[BM * BK];
  __shared__ unsigned short bt[BN * BK];

  const int tid  = threadIdx.x;
  const int lane = tid & 63;
  const int w    = tid >> 6;
  const int wm   = w >> 1;
  const int wn   = w & 1;

  f32x4 acc[4][4];
#pragma unroll
  for (int i = 0; i < 4; i++)
#pragma unroll
    for (int j = 0; j < 4; j++) acc[i][j] = (f32x4){0.f, 0.f, 0.f, 0.f};

  const int srow = lane >> 3;
  const int scol = (lane & 7) * 8;

  const int ntiles = Keff / BK;
  for (int kt = 0; kt < ntiles; ++kt) {
    const int k0 = kt * BK;
    if (kt) __syncthreads();
#pragma unroll
    for (int t = 0; t < 4; t++) {
      const int r = w * 32 + t * 8 + srow;
      gload_lds16(Ab + (long)r * lda + k0 + scol, &at[(w * 32 + t * 8) * BK + lane * 8]);
      gload_lds16(Bb + (long)r * ldb + k0 + scol, &bt[(w * 32 + t * 8) * BK + lane * 8]);
    }
    asm volatile("s_waitcnt vmcnt(0)" ::: "memory");
    __syncthreads();
#pragma unroll
    for (int kk = 0; kk < 2; ++kk) {
      bf16x8 af[4], bfr[4];
#pragma unroll
      for (int i = 0; i < 4; i++)
        af[i] = *(const bf16x8*)&at[(wm * 64 + i * 16 + (lane & 15)) * BK + kk * 32 + (lane >> 4) * 8];
#pragma unroll
      for (int j = 0; j < 4; j++)
        bfr[j] = *(const bf16x8*)&bt[(wn * 64 + j * 16 + (lane & 15)) * BK + kk * 32 + (lane >> 4) * 8];
#pragma unroll
      for (int i = 0; i < 4; i++)
#pragma unroll
        for (int j = 0; j < 4; j++)
          acc[i][j] = __builtin_amdgcn_mfma_f32_16x16x32_bf16(af[i], bfr[j], acc[i][j], 0, 0, 0);
    }
  }

  const long crow0 = (long)bi * BM + wm * 64;
  const long ccol0 = (long)bj * BN + wn * 64;
  if (outBf16) {
    unsigned short* C = (unsigned short*)Cout + (long)b * cBatch;
#pragma unroll
    for (int i = 0; i < 4; i++) {
      const long row0 = crow0 + i * 16 + ((lane >> 4) << 2);
#pragma unroll
      for (int j = 0; j < 4; j++) {
        const long col = ccol0 + j * 16 + (lane & 15);
#pragma unroll
        for (int r2 = 0; r2 < 4; r2++)
          C[(row0 + r2) * ldc + col] = f2bf(acc[i][j][r2] * scale);
      }
    }
  } else {
    float* C = (float*)Cout + (long)b * cBatch;
#pragma unroll
    for (int i = 0; i < 4; i++) {
      const long row0 = crow0 + i * 16 + ((lane >> 4) << 2);
#pragma unroll
      for (int j = 0; j < 4; j++) {
        const long col = ccol0 + j * 16 + (lane & 15);
#pragma unroll
        for (int r2 = 0; r2 < 4; r2++)
          C[(row0 + r2) * ldc + col] = acc[i][j][r2] * scale;
      }
    }
  }
}

// ---------------------------------------------------------------- softmax ---
// bf16 scores in, bf16 P out, zero-fill to 128 boundary.
__global__ __launch_bounds__(256)
void softmax_kernel(const unsigned short* __restrict__ scores, unsigned short* __restrict__ P) {
  __shared__ float rowbuf[SEQ];
  __shared__ float red[8];
  const int r = blockIdx.x;
  const int i = r & (SEQ - 1);
  const int n = i + 1;
  const int kend = ((i >> 7) + 1) << 7;
  const unsigned short* src = scores + (long)r * SEQ;
  unsigned short* dst = P + (long)r * SEQ;
  const int tid = threadIdx.x;

  float m = -1e30f;
  for (int j = tid; j < n; j += 256) { float v = bf2f(src[j]); rowbuf[j] = v; m = fmaxf(m, v); }
#pragma unroll
  for (int o = 32; o; o >>= 1) m = fmaxf(m, __shfl_down(m, o, 64));
  if ((tid & 63) == 0) red[tid >> 6] = m;
  __syncthreads();
  m = fmaxf(fmaxf(red[0], red[1]), fmaxf(red[2], red[3]));

  float s = 0.f;
  for (int j = tid; j < n; j += 256) { float e = __expf(rowbuf[j] - m); rowbuf[j] = e; s += e; }
#pragma unroll
  for (int o = 32; o; o >>= 1) s += __shfl_down(s, o, 64);
  if ((tid & 63) == 0) red[4 + (tid >> 6)] = s;
  __syncthreads();
  s = red[4] + red[5] + red[6] + red[7];
  const float inv = 1.0f / s;

  for (int j = tid; j < n; j += 256) dst[j] = f2bf(rowbuf[j] * inv);
  for (int j = n + tid; j < kend; j += 256) dst[j] = 0;
}

// ----------------------------------------------------------------- launch ---
extern "C" void kernel_launch(void* const* d_in, const int* in_sizes, int n_in,
                              void* d_out, int out_size, void* d_ws, size_t ws_size,
                              hipStream_t stream) {
  const float* x  = (const float*)d_in[0];
  const float* Wk = (const float*)d_in[1];
  const float* Wq = (const float*)d_in[2];
  const float* Wv = (const float*)d_in[3];

  char* ws = (char*)d_ws;
  unsigned short* xb      = (unsigned short*)(ws);                  // [8192][1024]
  unsigned short* qk      = (unsigned short*)(ws + 16777216);       // [8192][2048] q|k
  unsigned short* vtb     = (unsigned short*)(ws + 50331648);       // [1024][8192] V^T
  unsigned short* wkqb    = (unsigned short*)(ws + 67108864);       // [2048][1024] Wk|Wq
  unsigned short* wvb     = (unsigned short*)(ws + 71303168);       // [1024][1024]
  unsigned short* scoresb = (unsigned short*)(ws + 73400320);       // [4][2048][2048] bf16
  unsigned short* P       = (unsigned short*)(ws + 106954752);      // [4][2048][2048] bf16
  float* out = (float*)d_out;

  // 1. fp32 -> bf16
  {
    long total4 = ((long)MTOT * DIN + 3L * DOUT * DIN) / 4;
    int blocks = (int)((total4 + 255) / 256);
    convert_kernel<<<dim3(blocks), dim3(256), 0, stream>>>(x, Wk, Wq, Wv, xb, wkqb, wvb);
  }
  // 2. qk = x @ [Wk|Wq]^T : M=8192 N=2048 K=1024 on the 256^2 2-phase engine
  gemm256_kernel<<<dim3(2048 / TBN, 8192 / TBM), dim3(512), 0, stream>>>(
      xb, wkqb, qk, 1024, 1024, 2048, 1024);
  // 3. vT = Wv @ x^T : M=1024 N=8192 K=1024 (128^2 engine, 512 blocks)
  gemm_kernel<<<dim3(8192 / BN, 1024 / BM, 1), dim3(256), 0, stream>>>(
      wvb, xb, vtb, 1024, 1024, 8192, 1024, 0L, 0L, 0L, 1.0f, 1, 0, 0);
  // 4. scores = q@k^T * 1/32, exact lower-tri grid (136 blocks/batch), bf16 out
  gemm_kernel<<<dim3(136, 1, BATCH), dim3(256), 0, stream>>>(
      qk, qk + 1024, scoresb, 2048, 2048, 2048, 1024,
      (long)SEQ * 2048, (long)SEQ * 2048, (long)SEQ * SEQ, 0.03125f, 1, 1, 0);
  // 5. softmax (bf16 in/out)
  softmax_kernel<<<dim3(BATCH * SEQ), dim3(256), 0, stream>>>(scoresb, P);
  // 6. out = P@V (f32 out, K limited per row-block)
  gemm_kernel<<<dim3(1024 / BN, 2048 / BM, BATCH), dim3(256), 0, stream>>>(
      P, vtb, out, 2048, 8192, 1024, 2048,
      (long)SEQ * SEQ, 2048L, (long)SEQ * DOUT, 1.0f, 0, 0, 1);
}

// Round 3
// 255.946 us; speedup vs baseline: 1.1245x; 1.0388x over previous
//
#include <hip/hip_runtime.h>
#include <hip/hip_bf16.h>
#include <stdint.h>

#define BATCH 4
#define SEQ   2048
#define DIN   1024
#define DOUT  1024
#define MTOT  (BATCH*SEQ)   // 8192

typedef __attribute__((ext_vector_type(8))) short bf16x8;
typedef __attribute__((ext_vector_type(4))) float f32x4;
typedef unsigned short ushort_t;

__device__ inline unsigned short f2bf(float f) {
  union { float f; unsigned u; } a; a.f = f;
  unsigned r = a.u + 0x7fffu + ((a.u >> 16) & 1u);   // RTNE
  return (unsigned short)(r >> 16);
}
__device__ inline float bf2f(unsigned short b) {
  union { unsigned u; float f; } a; a.u = ((unsigned)b) << 16; return a.f;
}

__device__ inline void gload_lds16(const void* g, void* l) {
  __builtin_amdgcn_global_load_lds(
      (__attribute__((address_space(1))) void*)(uintptr_t)(g),
      (__attribute__((address_space(3))) void*)(uintptr_t)(l),
      16, 0, 0);
}

// ---------------------------------------------------------------- convert ---
__global__ __launch_bounds__(256)
void convert_kernel(const float* __restrict__ x, const float* __restrict__ wk,
                    const float* __restrict__ wq, const float* __restrict__ wv,
                    unsigned short* __restrict__ xb, unsigned short* __restrict__ wkqb,
                    unsigned short* __restrict__ wvb) {
  const long NX = (long)MTOT * DIN;      // 8388608
  const long NW = (long)DOUT * DIN;      // 1048576
  long t = (long)blockIdx.x * blockDim.x + threadIdx.x;
  long off = t * 4;
  if (off >= NX + 3 * NW) return;
  const float* src; unsigned short* dst; long o;
  if (off < NX)            { src = x;  dst = xb;        o = off; }
  else if (off < NX + NW)  { src = wk; dst = wkqb;      o = off - NX; }
  else if (off < NX + 2*NW){ src = wq; dst = wkqb + NW; o = off - NX - NW; }
  else                     { src = wv; dst = wvb;       o = off - NX - 2*NW; }
  f32x4 v = *(const f32x4*)(src + o);
  unsigned p0 = (unsigned)f2bf(v[0]) | ((unsigned)f2bf(v[1]) << 16);
  unsigned p1 = (unsigned)f2bf(v[2]) | ((unsigned)f2bf(v[3]) << 16);
  uint2* d = (uint2*)(dst + o);
  *d = make_uint2(p0, p1);
}

// -------------------------------------------- 256x128 3-buffer pipelined GEMM
// C[M][N] = A[M][K]*Bw[N][K]^T, bf16 out. 8 waves (4Mx2N), wave tile 64x64.
// 3 LDS buffers (144 KiB); stage tile t+2 while computing tile t; counted
// vmcnt(12) = 2 tiles in flight; raw s_barrier (no vmcnt(0) drain); XOR
// swizzle st(row&7)<<4 applied on the GLOBAL source + the ds_read address.
#define GBM 256
#define GBN 128
#define GBK 64

__device__ inline void stage3(const unsigned short* __restrict__ Ab,
                              const unsigned short* __restrict__ Bb,
                              int lda, int ldb, int k0,
                              unsigned short* at, unsigned short* bt, int tid) {
#pragma unroll
  for (int i = 0; i < 4; i++) {           // A: 256x64 = 32KB -> 4 x 16B/thread
    int idx = i * 512 + tid;              // 16B-chunk index
    int row = idx >> 3;                   // 8 chunks per 128B row
    int cb  = (idx & 7) << 4;
    int cbs = cb ^ ((row & 7) << 4);      // pre-swizzled global source
    gload_lds16((const char*)Ab + (long)row * (lda * 2) + k0 * 2 + cbs,
                (char*)at + idx * 16);    // linear LDS dest (base + lane*16)
  }
#pragma unroll
  for (int i = 0; i < 2; i++) {           // B: 128x64 = 16KB -> 2 x 16B/thread
    int idx = i * 512 + tid;
    int row = idx >> 3;
    int cb  = (idx & 7) << 4;
    int cbs = cb ^ ((row & 7) << 4);
    gload_lds16((const char*)Bb + (long)row * (ldb * 2) + k0 * 2 + cbs,
                (char*)bt + idx * 16);
  }
}

__device__ inline void compute3(const unsigned short* at, const unsigned short* bt,
                                int lane, int wm, int wn, f32x4 acc[4][4]) {
#pragma unroll
  for (int kk = 0; kk < 2; kk++) {
    bf16x8 af[4], bfr[4];
#pragma unroll
    for (int ii = 0; ii < 4; ii++) {
      int row = wm * 64 + ii * 16 + (lane & 15);
      int cb  = (kk * 64 + ((lane >> 4) << 4)) ^ ((row & 7) << 4);
      af[ii] = *(const bf16x8*)((const char*)at + row * 128 + cb);
    }
#pragma unroll
    for (int j = 0; j < 4; j++) {
      int row = wn * 64 + j * 16 + (lane & 15);
      int cb  = (kk * 64 + ((lane >> 4) << 4)) ^ ((row & 7) << 4);
      bfr[j] = *(const bf16x8*)((const char*)bt + row * 128 + cb);
    }
    __builtin_amdgcn_s_setprio(1);
#pragma unroll
    for (int ii = 0; ii < 4; ii++)
#pragma unroll
      for (int j = 0; j < 4; j++)
        acc[ii][j] = __builtin_amdgcn_mfma_f32_16x16x32_bf16(af[ii], bfr[j], acc[ii][j], 0, 0, 0);
    __builtin_amdgcn_s_setprio(0);
  }
}

__global__ __launch_bounds__(512, 2)
void gemm3_kernel(const unsigned short* __restrict__ A,
                  const unsigned short* __restrict__ Bw,
                  unsigned short* __restrict__ C,
                  int lda, int ldb, int ldc, int K) {
  __shared__ unsigned short at[3][GBM * GBK];   // 3 x 32 KiB
  __shared__ unsigned short bt[3][GBN * GBK];   // 3 x 16 KiB
  const int bj = blockIdx.x, bi = blockIdx.y;
  const unsigned short* Ab = A + (long)bi * GBM * lda;
  const unsigned short* Bb = Bw + (long)bj * GBN * ldb;
  const int tid = threadIdx.x, lane = tid & 63, w = tid >> 6;
  const int wm = w >> 1, wn = w & 1;

  f32x4 acc[4][4];
#pragma unroll
  for (int i = 0; i < 4; i++)
#pragma unroll
    for (int j = 0; j < 4; j++) acc[i][j] = (f32x4){0.f, 0.f, 0.f, 0.f};

  const int nt = K / GBK;   // 16 for K=1024
  unsigned short *a0 = at[0], *a1 = at[1], *a2 = at[2];
  unsigned short *b0 = bt[0], *b1 = bt[1], *b2 = bt[2];

  stage3(Ab, Bb, lda, ldb, 0,      a0, b0, tid);
  stage3(Ab, Bb, lda, ldb, GBK,    a1, b1, tid);

  for (int t = 0; t < nt; t++) {
    if (t + 2 < nt) stage3(Ab, Bb, lda, ldb, (t + 2) * GBK, a2, b2, tid);
    asm volatile("s_waitcnt vmcnt(12)" ::: "memory");   // tile t drained (FIFO)
    __builtin_amdgcn_s_barrier();
    asm volatile("" ::: "memory");
    compute3(a0, b0, lane, wm, wn, acc);
    asm volatile("" ::: "memory");
    __builtin_amdgcn_s_barrier();                        // reads done before reuse
    unsigned short* ta = a0; a0 = a1; a1 = a2; a2 = ta;
    unsigned short* tb = b0; b0 = b1; b1 = b2; b2 = tb;
  }

  const long crow0 = (long)bi * GBM + wm * 64;
  const long ccol0 = (long)bj * GBN + wn * 64;
#pragma unroll
  for (int i = 0; i < 4; i++) {
    const long row0 = crow0 + i * 16 + ((lane >> 4) << 2);
#pragma unroll
    for (int j = 0; j < 4; j++) {
      const long col = ccol0 + j * 16 + (lane & 15);
#pragma unroll
      for (int r2 = 0; r2 < 4; r2++)
        C[(row0 + r2) * ldc + col] = f2bf(acc[i][j][r2]);
    }
  }
}

// ----------------------------------------------------------- 128x128 GEMM ---
#define BM 128
#define BN 128
#define BK 64

__global__ __launch_bounds__(256, 2)
void gemm_kernel(const unsigned short* __restrict__ A,
                 const unsigned short* __restrict__ Bw,
                 void* __restrict__ Cout,
                 int lda, int ldb, int ldc, int K,
                 long aBatch, long bBatch, long cBatch,
                 float scale, int outBf16, int triPack, int klimit, int balance) {
  int bj = blockIdx.x, bi = blockIdx.y, b = blockIdx.z;
  if (triPack) {                      // exact lower-tri grid
    int idx = blockIdx.x;
    int t = (int)((sqrtf(8.f * idx + 1.f) - 1.f) * 0.5f);
    while ((t + 1) * (t + 2) / 2 <= idx) t++;
    while (t * (t + 1) / 2 > idx) t--;
    bi = t; bj = idx - t * (t + 1) / 2;
  }
  if (balance) {                      // interleave small/large K blocks
    int y = bi, h = y >> 1;
    y = (y & 1) ? 15 - h : h;
    if (b >= 2) y = 15 - y;
    bi = y;
  }
  int Keff = K;
  if (klimit) { int km = (bi + 1) * BM; Keff = km < K ? km : K; }

  const unsigned short* Ab = A  + (long)b * aBatch + (long)bi * BM * lda;
  const unsigned short* Bb = Bw + (long)b * bBatch + (long)bj * BN * ldb;

  __shared__ unsigned short at[BM * BK];
  __shared__ unsigned short bt[BN * BK];

  const int tid  = threadIdx.x;
  const int lane = tid & 63;
  const int w    = tid >> 6;
  const int wm   = w >> 1;
  const int wn   = w & 1;

  f32x4 acc[4][4];
#pragma unroll
  for (int i = 0; i < 4; i++)
#pragma unroll
    for (int j = 0; j < 4; j++) acc[i][j] = (f32x4){0.f, 0.f, 0.f, 0.f};

  const int srow = lane >> 3;
  const int scol = (lane & 7) * 8;

  const int ntiles = Keff / BK;
  for (int kt = 0; kt < ntiles; ++kt) {
    const int k0 = kt * BK;
    if (kt) __syncthreads();
#pragma unroll
    for (int t = 0; t < 4; t++) {
      const int r = w * 32 + t * 8 + srow;
      gload_lds16(Ab + (long)r * lda + k0 + scol, &at[(w * 32 + t * 8) * BK + lane * 8]);
      gload_lds16(Bb + (long)r * ldb + k0 + scol, &bt[(w * 32 + t * 8) * BK + lane * 8]);
    }
    asm volatile("s_waitcnt vmcnt(0)" ::: "memory");
    __syncthreads();
#pragma unroll
    for (int kk = 0; kk < 2; ++kk) {
      bf16x8 af[4], bfr[4];
#pragma unroll
      for (int i = 0; i < 4; i++)
        af[i] = *(const bf16x8*)&at[(wm * 64 + i * 16 + (lane & 15)) * BK + kk * 32 + (lane >> 4) * 8];
#pragma unroll
      for (int j = 0; j < 4; j++)
        bfr[j] = *(const bf16x8*)&bt[(wn * 64 + j * 16 + (lane & 15)) * BK + kk * 32 + (lane >> 4) * 8];
#pragma unroll
      for (int i = 0; i < 4; i++)
#pragma unroll
        for (int j = 0; j < 4; j++)
          acc[i][j] = __builtin_amdgcn_mfma_f32_16x16x32_bf16(af[i], bfr[j], acc[i][j], 0, 0, 0);
    }
  }

  const long crow0 = (long)bi * BM + wm * 64;
  const long ccol0 = (long)bj * BN + wn * 64;
  if (outBf16) {
    unsigned short* C = (unsigned short*)Cout + (long)b * cBatch;
#pragma unroll
    for (int i = 0; i < 4; i++) {
      const long row0 = crow0 + i * 16 + ((lane >> 4) << 2);
#pragma unroll
      for (int j = 0; j < 4; j++) {
        const long col = ccol0 + j * 16 + (lane & 15);
#pragma unroll
        for (int r2 = 0; r2 < 4; r2++)
          C[(row0 + r2) * ldc + col] = f2bf(acc[i][j][r2] * scale);
      }
    }
  } else {
    float* C = (float*)Cout + (long)b * cBatch;
#pragma unroll
    for (int i = 0; i < 4; i++) {
      const long row0 = crow0 + i * 16 + ((lane >> 4) << 2);
#pragma unroll
      for (int j = 0; j < 4; j++) {
        const long col = ccol0 + j * 16 + (lane & 15);
#pragma unroll
        for (int r2 = 0; r2 < 4; r2++)
          C[(row0 + r2) * ldc + col] = acc[i][j][r2] * scale;
      }
    }
  }
}

// -------------------------------------------------------------- transpose ---
// vtb[e][m] = qkv[m][2048+e]; 64x64 tiles.
__global__ __launch_bounds__(256)
void transpose_kernel(const unsigned short* __restrict__ qkv, unsigned short* __restrict__ vtb) {
  __shared__ unsigned short lds[64][65];
  const int m0 = blockIdx.x * 64, e0 = blockIdx.y * 64;
  const int t = threadIdx.x;
  const int r = t >> 3, c = (t & 7) * 8;
#pragma unroll
  for (int h = 0; h < 2; h++) {
    const int rr = r + h * 32;
    uint4 raw = *(const uint4*)(qkv + (long)(m0 + rr) * 3072 + 2048 + e0 + c);
    const unsigned short* u = (const unsigned short*)&raw;
#pragma unroll
    for (int k = 0; k < 8; k++) lds[rr][c + k] = u[k];
  }
  __syncthreads();
#pragma unroll
  for (int h = 0; h < 2; h++) {
    const int er = r + h * 32;
    unsigned short v[8];
#pragma unroll
    for (int k = 0; k < 8; k++) v[k] = lds[c + k][er];
    *(uint4*)(vtb + (long)(e0 + er) * 8192 + m0 + c) = *(const uint4*)v;
  }
}

// ---------------------------------------------------------------- softmax ---
// One WAVE per row; row held in registers (32 f32/lane).
__global__ __launch_bounds__(256)
void softmax_kernel(const unsigned short* __restrict__ scores, unsigned short* __restrict__ P) {
  const int w = threadIdx.x >> 6, lane = threadIdx.x & 63;
  const int r = blockIdx.x * 4 + w;       // 0..8191
  const int i = r & (SEQ - 1);
  const int kend = ((i >> 7) + 1) << 7;   // 128-block boundary
  const unsigned short* src = scores + (long)r * SEQ;
  unsigned short* dst = P + (long)r * SEQ;

  float e[4][8];
  float m = -1e30f;
#pragma unroll
  for (int c = 0; c < 4; c++) {
    const int j0 = c * 512 + lane * 8;
    if (j0 < kend) {
      uint4 raw = *(const uint4*)(src + j0);
      const unsigned short* u = (const unsigned short*)&raw;
#pragma unroll
      for (int k = 0; k < 8; k++) {
        float v = bf2f(u[k]);
        e[c][k] = (j0 + k <= i) ? v : -1e30f;
        m = fmaxf(m, e[c][k]);
      }
    } else {
#pragma unroll
      for (int k = 0; k < 8; k++) e[c][k] = -1e30f;
    }
  }
#pragma unroll
  for (int o = 32; o; o >>= 1) m = fmaxf(m, __shfl_xor(m, o, 64));

  float s = 0.f;
#pragma unroll
  for (int c = 0; c < 4; c++)
#pragma unroll
    for (int k = 0; k < 8; k++) {
      float x = (e[c][k] > -1e29f) ? __expf(e[c][k] - m) : 0.f;
      e[c][k] = x; s += x;
    }
#pragma unroll
  for (int o = 32; o; o >>= 1) s += __shfl_xor(s, o, 64);
  const float inv = 1.0f / s;

#pragma unroll
  for (int c = 0; c < 4; c++) {
    const int j0 = c * 512 + lane * 8;
    if (j0 < kend) {
      unsigned short v[8];
#pragma unroll
      for (int k = 0; k < 8; k++) v[k] = f2bf(e[c][k] * inv);
      *(uint4*)(dst + j0) = *(const uint4*)v;
    }
  }
}

// ----------------------------------------------------------------- launch ---
extern "C" void kernel_launch(void* const* d_in, const int* in_sizes, int n_in,
                              void* d_out, int out_size, void* d_ws, size_t ws_size,
                              hipStream_t stream) {
  const float* x  = (const float*)d_in[0];
  const float* Wk = (const float*)d_in[1];
  const float* Wq = (const float*)d_in[2];
  const float* Wv = (const float*)d_in[3];

  char* ws = (char*)d_ws;
  unsigned short* xb      = (unsigned short*)(ws);                  // [8192][1024]
  unsigned short* qkv     = (unsigned short*)(ws + 16777216);       // [8192][3072] q|k|v
  unsigned short* vtb     = (unsigned short*)(ws + 67108864);       // [1024][8192] V^T
  unsigned short* wb      = (unsigned short*)(ws + 83886080);       // [3072][1024] Wk|Wq|Wv
  unsigned short* scoresb = (unsigned short*)(ws + 90177536);       // [4][2048][2048] bf16
  unsigned short* P       = (unsigned short*)(ws + 123731968);      // [4][2048][2048] bf16
  float* out = (float*)d_out;

  // 1. fp32 -> bf16
  {
    long total4 = ((long)MTOT * DIN + 3L * DOUT * DIN) / 4;
    int blocks = (int)((total4 + 255) / 256);
    convert_kernel<<<dim3(blocks), dim3(256), 0, stream>>>(x, Wk, Wq, Wv, xb, wb, wb + 2 * 1048576);
  }
  // 2. qkv = x @ [Wk|Wq|Wv]^T : M=8192 N=3072 K=1024, 3-buffer engine, 768 blocks
  gemm3_kernel<<<dim3(3072 / GBN, 8192 / GBM), dim3(512), 0, stream>>>(
      xb, wb, qkv, 1024, 1024, 3072, 1024);
  // 3. vtb = transpose of V part (cols 2048..3071)
  transpose_kernel<<<dim3(8192 / 64, 1024 / 64), dim3(256), 0, stream>>>(qkv, vtb);
  // 4. scores = q@k^T * 1/32, lower-tri grid, bf16 out
  gemm_kernel<<<dim3(136, 1, BATCH), dim3(256), 0, stream>>>(
      qkv, qkv + 1024, scoresb, 3072, 3072, 2048, 1024,
      (long)SEQ * 3072, (long)SEQ * 3072, (long)SEQ * SEQ, 0.03125f, 1, 1, 0, 0);
  // 5. softmax (wave per row)
  softmax_kernel<<<dim3(BATCH * SEQ / 4), dim3(256), 0, stream>>>(scoresb, P);
  // 6. out = P@V (f32 out, K limited per row-block, balanced)
  gemm_kernel<<<dim3(1024 / BN, 2048 / BM, BATCH), dim3(256), 0, stream>>>(
      P, vtb, out, 2048, 8192, 1024, 2048,
      (long)SEQ * SEQ, 2048L, (long)SEQ * DOUT, 1.0f, 0, 0, 1, 1);
}

// Round 5
// 253.352 us; speedup vs baseline: 1.1360x; 1.0102x over previous
//
#include <hip/hip_runtime.h>
#include <hip/hip_bf16.h>
#include <stdint.h>

#define BATCH 4
#define SEQ   2048
#define DIN   1024
#define DOUT  1024
#define MTOT  (BATCH*SEQ)   // 8192

typedef __attribute__((ext_vector_type(8))) short bf16x8;
typedef __attribute__((ext_vector_type(4))) float f32x4;

__device__ inline unsigned short f2bf(float f) {
  union { float f; unsigned u; } a; a.f = f;
  unsigned r = a.u + 0x7fffu + ((a.u >> 16) & 1u);   // RTNE
  return (unsigned short)(r >> 16);
}
__device__ inline float bf2f(unsigned short b) {
  union { unsigned u; float f; } a; a.u = ((unsigned)b) << 16; return a.f;
}

__device__ inline void gload_lds16(const void* g, void* l) {
  __builtin_amdgcn_global_load_lds(
      (__attribute__((address_space(1))) void*)(uintptr_t)(g),
      (__attribute__((address_space(3))) void*)(uintptr_t)(l),
      16, 0, 0);
}

// ---------------------------------------------------------------- convert ---
__global__ __launch_bounds__(256)
void convert_kernel(const float* __restrict__ x, const float* __restrict__ wk,
                    const float* __restrict__ wq, const float* __restrict__ wv,
                    unsigned short* __restrict__ xb, unsigned short* __restrict__ wkqb,
                    unsigned short* __restrict__ wvb) {
  const long NX = (long)MTOT * DIN;      // 8388608
  const long NW = (long)DOUT * DIN;      // 1048576
  long t = (long)blockIdx.x * blockDim.x + threadIdx.x;
  long off = t * 4;
  if (off >= NX + 3 * NW) return;
  const float* src; unsigned short* dst; long o;
  if (off < NX)            { src = x;  dst = xb;        o = off; }
  else if (off < NX + NW)  { src = wk; dst = wkqb;      o = off - NX; }
  else if (off < NX + 2*NW){ src = wq; dst = wkqb + NW; o = off - NX - NW; }
  else                     { src = wv; dst = wvb;       o = off - NX - 2*NW; }
  f32x4 v = *(const f32x4*)(src + o);
  unsigned p0 = (unsigned)f2bf(v[0]) | ((unsigned)f2bf(v[1]) << 16);
  unsigned p1 = (unsigned)f2bf(v[2]) | ((unsigned)f2bf(v[3]) << 16);
  uint2* d = (uint2*)(dst + o);
  *d = make_uint2(p0, p1);
}

// -------------------------------------- 256x128 8-wave phase-interleaved GEMM
// C[M][N] = A[M][K]*Bw[N][K]^T. BK=64, dbuf LDS (96 KiB), XOR-swizzled.
// Per K-tile: 4 phases {ds_read subtile; stage next-tile chunk; barrier;
// setprio(1); 8 MFMA; setprio(0); barrier}. One vmcnt(0)+barrier per tile,
// draining only loads issued >=3 phases earlier (counted-by-construction).
__device__ inline void stage8A(const unsigned short* __restrict__ Ab, int ldab,
                               int k0b, unsigned short* at, int tid) {
#pragma unroll
  for (int u = 0; u < 4; u++) {           // A: 256x64 = 32KB
    int idx = u * 512 + tid;
    int row = idx >> 3;
    int cb  = (idx & 7) << 4;
    int cbs = cb ^ ((row & 7) << 4);      // pre-swizzled global source
    gload_lds16((const char*)Ab + (long)row * ldab + k0b + cbs,
                (char*)at + idx * 16);
  }
}
__device__ inline void stage8B(const unsigned short* __restrict__ Bb, int ldbb,
                               int k0b, unsigned short* bt, int tid) {
#pragma unroll
  for (int u = 0; u < 2; u++) {           // B: 128x64 = 16KB
    int idx = u * 512 + tid;
    int row = idx >> 3;
    int cb  = (idx & 7) << 4;
    int cbs = cb ^ ((row & 7) << 4);
    gload_lds16((const char*)Bb + (long)row * ldbb + k0b + cbs,
                (char*)bt + idx * 16);
  }
}

__global__ __launch_bounds__(512, 2)
void gemm8_kernel(const unsigned short* __restrict__ A,
                  const unsigned short* __restrict__ Bw,
                  void* __restrict__ Cout,
                  int lda, int ldb, int ldc, int K,
                  long aBatch, long bBatch, long cBatch,
                  float scale, int outBf16, int tri, int swiz) {
  __shared__ unsigned short at[2][256 * 64];   // 2 x 32 KiB
  __shared__ unsigned short bt[2][128 * 64];   // 2 x 16 KiB
  int bi, bj;
  const int b = blockIdx.z;
  if (tri) {                                   // 256row x 128col lower-tri tiles
    int idx = blockIdx.x;                      // R: idx in [R(R+1), (R+1)(R+2))
    int R = (int)((sqrtf(4.f * idx + 1.f) - 1.f) * 0.5f);
    while ((R + 1) * (R + 2) <= idx) R++;
    while (R * (R + 1) > idx) R--;
    bi = R; bj = idx - R * (R + 1);
  } else if (swiz) {                           // XCD-contiguous remap (nwg%8==0)
    int nx = gridDim.x;
    int wg = blockIdx.y * nx + blockIdx.x;
    int nwg = nx * gridDim.y;
    int q = nwg >> 3;
    int s = (wg & 7) * q + (wg >> 3);
    bi = s / nx; bj = s % nx;
  } else { bi = blockIdx.y; bj = blockIdx.x; }

  const unsigned short* Ab = A  + (long)b * aBatch + (long)bi * 256 * lda;
  const unsigned short* Bb = Bw + (long)b * bBatch + (long)bj * 128 * ldb;
  const int ldab = lda * 2, ldbb = ldb * 2;
  const int tid = threadIdx.x, lane = tid & 63, w = tid >> 6;
  const int wm = w >> 1, wn = w & 1;           // wave tile 64x64 at (wm, wn)

  f32x4 acc[4][4];
#pragma unroll
  for (int i = 0; i < 4; i++)
#pragma unroll
    for (int j = 0; j < 4; j++) acc[i][j] = (f32x4){0.f, 0.f, 0.f, 0.f};

  stage8A(Ab, ldab, 0, at[0], tid);            // prologue: tile 0
  stage8B(Bb, ldbb, 0, bt[0], tid);

  const int nt = K / 64;
  for (int t = 0; t < nt; ++t) {
    const unsigned short* a  = at[t & 1];
    const unsigned short* bb = bt[t & 1];
    unsigned short* an = at[(t & 1) ^ 1];
    unsigned short* bn = bt[(t & 1) ^ 1];
    const int last = (t + 1 >= nt);
    const int k0b = (t + 1) * 128;             // next tile K-offset in bytes

    // ---- tile entry: drain tile t's stages (issued >=3 phases ago) ----
    asm volatile("s_waitcnt vmcnt(0)" ::: "memory");
    __builtin_amdgcn_s_barrier();
    asm volatile("" ::: "memory");

    // ---- phase 0: read all B frags + A frag i=0; stage next A ----
    bf16x8 bf[4][2];
#pragma unroll
    for (int j = 0; j < 4; j++) {
      int row = wn * 64 + j * 16 + (lane & 15);
#pragma unroll
      for (int kk = 0; kk < 2; kk++) {
        int cb = (kk * 64 + ((lane >> 4) << 4)) ^ ((row & 7) << 4);
        bf[j][kk] = *(const bf16x8*)((const char*)bb + row * 128 + cb);
      }
    }
    bf16x8 af0[2];
    {
      int row = wm * 64 + (lane & 15);
#pragma unroll
      for (int kk = 0; kk < 2; kk++) {
        int cb = (kk * 64 + ((lane >> 4) << 4)) ^ ((row & 7) << 4);
        af0[kk] = *(const bf16x8*)((const char*)a + row * 128 + cb);
      }
    }
    if (!last) stage8A(Ab, ldab, k0b, an, tid);
    __builtin_amdgcn_s_barrier();
    __builtin_amdgcn_s_setprio(1);
#pragma unroll
    for (int kk = 0; kk < 2; kk++)
#pragma unroll
      for (int j = 0; j < 4; j++)
        acc[0][j] = __builtin_amdgcn_mfma_f32_16x16x32_bf16(af0[kk], bf[j][kk], acc[0][j], 0, 0, 0);
    __builtin_amdgcn_s_setprio(0);
    __builtin_amdgcn_s_barrier();

    // ---- phases 1..3: read A frag i=q; stage next B at q==1 ----
#pragma unroll
    for (int q = 1; q < 4; q++) {
      bf16x8 afq[2];
      int row = wm * 64 + q * 16 + (lane & 15);
#pragma unroll
      for (int kk = 0; kk < 2; kk++) {
        int cb = (kk * 64 + ((lane >> 4) << 4)) ^ ((row & 7) << 4);
        afq[kk] = *(const bf16x8*)((const char*)a + row * 128 + cb);
      }
      if (q == 1 && !last) stage8B(Bb, ldbb, k0b, bn, tid);
      __builtin_amdgcn_s_barrier();
      __builtin_amdgcn_s_setprio(1);
#pragma unroll
      for (int kk = 0; kk < 2; kk++)
#pragma unroll
        for (int j = 0; j < 4; j++)
          acc[q][j] = __builtin_amdgcn_mfma_f32_16x16x32_bf16(afq[kk], bf[j][kk], acc[q][j], 0, 0, 0);
      __builtin_amdgcn_s_setprio(0);
      __builtin_amdgcn_s_barrier();
    }
  }

  const long crow0 = (long)bi * 256 + wm * 64;
  const long ccol0 = (long)bj * 128 + wn * 64;
  if (outBf16) {
    unsigned short* C = (unsigned short*)Cout + (long)b * cBatch;
#pragma unroll
    for (int i = 0; i < 4; i++) {
      const long row0 = crow0 + i * 16 + ((lane >> 4) << 2);
#pragma unroll
      for (int j = 0; j < 4; j++) {
        const long col = ccol0 + j * 16 + (lane & 15);
#pragma unroll
        for (int r2 = 0; r2 < 4; r2++)
          C[(row0 + r2) * ldc + col] = f2bf(acc[i][j][r2] * scale);
      }
    }
  } else {
    float* C = (float*)Cout + (long)b * cBatch;
#pragma unroll
    for (int i = 0; i < 4; i++) {
      const long row0 = crow0 + i * 16 + ((lane >> 4) << 2);
#pragma unroll
      for (int j = 0; j < 4; j++) {
        const long col = ccol0 + j * 16 + (lane & 15);
#pragma unroll
        for (int r2 = 0; r2 < 4; r2++)
          C[(row0 + r2) * ldc + col] = acc[i][j][r2] * scale;
      }
    }
  }
}

// -------------------------------------------------------------- transpose ---
// vtb[e][m] = qkv[m][2048+e]; 64x64 tiles.
__global__ __launch_bounds__(256)
void transpose_kernel(const unsigned short* __restrict__ qkv, unsigned short* __restrict__ vtb) {
  __shared__ unsigned short lds[64][65];
  const int m0 = blockIdx.x * 64, e0 = blockIdx.y * 64;
  const int t = threadIdx.x;
  const int r = t >> 3, c = (t & 7) * 8;
#pragma unroll
  for (int h = 0; h < 2; h++) {
    const int rr = r + h * 32;
    uint4 raw = *(const uint4*)(qkv + (long)(m0 + rr) * 3072 + 2048 + e0 + c);
    const unsigned short* u = (const unsigned short*)&raw;
#pragma unroll
    for (int k = 0; k < 8; k++) lds[rr][c + k] = u[k];
  }
  __syncthreads();
#pragma unroll
  for (int h = 0; h < 2; h++) {
    const int er = r + h * 32;
    unsigned short v[8];
#pragma unroll
    for (int k = 0; k < 8; k++) v[k] = lds[c + k][er];
    *(uint4*)(vtb + (long)(e0 + er) * 8192 + m0 + c) = *(const uint4*)v;
  }
}

// ---------------------------------------------------------------- softmax ---
// One WAVE per row; row in registers. Full-row write (zeros past the causal
// boundary) so PV can run as a uniform K=2048 GEMM.
__global__ __launch_bounds__(256)
void softmax_kernel(const unsigned short* __restrict__ scores, unsigned short* __restrict__ P) {
  const int w = threadIdx.x >> 6, lane = threadIdx.x & 63;
  const int r = blockIdx.x * 4 + w;       // 0..8191
  const int i = r & (SEQ - 1);
  const int kend = ((i >> 7) + 1) << 7;   // cols >= kend were never written
  const unsigned short* src = scores + (long)r * SEQ;
  unsigned short* dst = P + (long)r * SEQ;

  float e[4][8];
  float m = -1e30f;
#pragma unroll
  for (int c = 0; c < 4; c++) {
    const int j0 = c * 512 + lane * 8;
    if (j0 < kend) {
      uint4 raw = *(const uint4*)(src + j0);
      const unsigned short* u = (const unsigned short*)&raw;
#pragma unroll
      for (int k = 0; k < 8; k++) {
        float v = bf2f(u[k]);
        e[c][k] = (j0 + k <= i) ? v : -1e30f;
        m = fmaxf(m, e[c][k]);
      }
    } else {
#pragma unroll
      for (int k = 0; k < 8; k++) e[c][k] = -1e30f;
    }
  }
#pragma unroll
  for (int o = 32; o; o >>= 1) m = fmaxf(m, __shfl_xor(m, o, 64));

  float s = 0.f;
#pragma unroll
  for (int c = 0; c < 4; c++)
#pragma unroll
    for (int k = 0; k < 8; k++) {
      float x = (e[c][k] > -1e29f) ? __expf(e[c][k] - m) : 0.f;
      e[c][k] = x; s += x;
    }
#pragma unroll
  for (int o = 32; o; o >>= 1) s += __shfl_xor(s, o, 64);
  const float inv = 1.0f / s;

#pragma unroll
  for (int c = 0; c < 4; c++) {
    const int j0 = c * 512 + lane * 8;
    unsigned short v[8];
#pragma unroll
    for (int k = 0; k < 8; k++) v[k] = f2bf(e[c][k] * inv);
    *(uint4*)(dst + j0) = *(const uint4*)v;
  }
}

// ----------------------------------------------------------------- launch ---
extern "C" void kernel_launch(void* const* d_in, const int* in_sizes, int n_in,
                              void* d_out, int out_size, void* d_ws, size_t ws_size,
                              hipStream_t stream) {
  const float* x  = (const float*)d_in[0];
  const float* Wk = (const float*)d_in[1];
  const float* Wq = (const float*)d_in[2];
  const float* Wv = (const float*)d_in[3];

  char* ws = (char*)d_ws;
  unsigned short* xb      = (unsigned short*)(ws);                  // [8192][1024]
  unsigned short* qkv     = (unsigned short*)(ws + 16777216);       // [8192][3072] q|k|v
  unsigned short* vtb     = (unsigned short*)(ws + 67108864);       // [1024][8192] V^T
  unsigned short* wb      = (unsigned short*)(ws + 83886080);       // [3072][1024] Wk|Wq|Wv
  unsigned short* scoresb = (unsigned short*)(ws + 90177536);       // [4][2048][2048] bf16
  unsigned short* P       = (unsigned short*)(ws + 123731968);      // [4][2048][2048] bf16
  float* out = (float*)d_out;

  // 1. fp32 -> bf16
  {
    long total4 = ((long)MTOT * DIN + 3L * DOUT * DIN) / 4;
    int blocks = (int)((total4 + 255) / 256);
    convert_kernel<<<dim3(blocks), dim3(256), 0, stream>>>(x, Wk, Wq, Wv, xb, wb, wb + 2 * 1048576);
  }
  // 2. qkv = x @ [Wk|Wq|Wv]^T : M=8192 N=3072 K=1024 (768 blocks, XCD-swizzled)
  gemm8_kernel<<<dim3(3072 / 128, 8192 / 256, 1), dim3(512), 0, stream>>>(
      xb, wb, qkv, 1024, 1024, 3072, 1024, 0L, 0L, 0L, 1.0f, 1, 0, 1);
  // 3. vtb = transpose of V part (cols 2048..3071)
  transpose_kernel<<<dim3(8192 / 64, 1024 / 64), dim3(256), 0, stream>>>(qkv, vtb);
  // 4. scores = q@k^T * 1/32, exact lower-tri 256x128 grid (72 tiles/batch)
  gemm8_kernel<<<dim3(72, 1, BATCH), dim3(512), 0, stream>>>(
      qkv, qkv + 1024, scoresb, 3072, 3072, 2048, 1024,
      (long)SEQ * 3072, (long)SEQ * 3072, (long)SEQ * SEQ, 0.03125f, 1, 1, 0);
  // 5. softmax (wave per row, full-row zero-filled output)
  softmax_kernel<<<dim3(BATCH * SEQ / 4), dim3(256), 0, stream>>>(scoresb, P);
  // 6. out = P@V : uniform K=2048, 256 blocks = exactly 1/CU, f32 out
  gemm8_kernel<<<dim3(1024 / 128, 2048 / 256, BATCH), dim3(512), 0, stream>>>(
      P, vtb, out, 2048, 8192, 1024, 2048,
      (long)SEQ * SEQ, 2048L, (long)SEQ * DOUT, 1.0f, 0, 0, 1);
}